// Round 1
// baseline (226.310 us; speedup 1.0000x reference)
//
#include <hip/hip_runtime.h>
#include <hip/hip_bf16.h>
#include <cstdint>

// GQA prefill: b=2, t=1024, E=2048, NQ=32, NKV=8, HD=64. fp32 in/out, bf16 MFMA inside.

typedef __attribute__((ext_vector_type(8))) short short8;   // 8 bf16 (MFMA A/B frag)
typedef __attribute__((ext_vector_type(4))) short short4v;
typedef __attribute__((ext_vector_type(4))) float f32x4;    // MFMA C/D frag

__device__ inline short f2b(float f) {  // fp32 -> bf16 (RNE)
  union { float f; unsigned u; } v; v.f = f;
  unsigned r = v.u + 0x7fffu + ((v.u >> 16) & 1u);
  return (short)(r >> 16);
}

__device__ inline float exp2_fast(float x) {
  float r;
  asm("v_exp_f32 %0, %1" : "=v"(r) : "v"(x));
  return r;
}

__device__ inline void gl_lds16(const void* g, void* l) {
  // async global->LDS, 16B/lane; LDS dest = wave-uniform base + lane*16
  __builtin_amdgcn_global_load_lds((const __attribute__((address_space(1))) void*)g,
                                   (__attribute__((address_space(3))) void*)l,
                                   16, 0, 0);
}

// ---------------- elementwise cast x -> bf16 ----------------
__global__ void cast_x_kernel(const float* __restrict__ x, short* __restrict__ xb, int n4) {
  int i = blockIdx.x * 256 + threadIdx.x;
  if (i >= n4) return;
  float4 v = ((const float4*)x)[i];
  short4v o; o.x = f2b(v.x); o.y = f2b(v.y); o.z = f2b(v.z); o.w = f2b(v.w);
  ((short4v*)xb)[i] = o;
}

// ---------------- all weight transposes in one launch ----------------
// grid (80, 32): x<32 wq | <40 wk | <48 wv | else wo. 64x64 LDS tile each.
__global__ void wtrans_all(const float* __restrict__ wq, const float* __restrict__ wk,
                           const float* __restrict__ wv, const float* __restrict__ wo,
                           short* __restrict__ WqkvT, short* __restrict__ woT) {
  __shared__ float tile[64][65];
  const int bx = blockIdx.x;
  const float* W; short* WT; int N, off, nb;
  if (bx < 32)      { W = wq; WT = WqkvT; N = 2048; off = 0;    nb = bx * 64; }
  else if (bx < 40) { W = wk; WT = WqkvT; N = 512;  off = 2048; nb = (bx - 32) * 64; }
  else if (bx < 48) { W = wv; WT = WqkvT; N = 512;  off = 2560; nb = (bx - 40) * 64; }
  else              { W = wo; WT = woT;   N = 2048; off = 0;    nb = (bx - 48) * 64; }
  const int kb = blockIdx.y * 64;
  const int tid = threadIdx.x;
  const int c = tid & 63, r0 = tid >> 6;
#pragma unroll
  for (int s = 0; s < 16; ++s) {
    int k = r0 + s * 4;
    tile[c][k] = W[(size_t)(kb + k) * N + nb + c];
  }
  __syncthreads();
#pragma unroll
  for (int s = 0; s < 16; ++s) {
    int n = r0 + s * 4;
    WT[(size_t)(off + nb + n) * 2048 + kb + c] = f2b(tile[n][c]);
  }
}

// ---------------- shared K-loop: 128(M)x64(N) tile, K=2048 ----------------
// NEW (T2+T3+T4+T5): BK=32 half-stages, 4 half-buffers in the same 48KB LDS,
// depth-3 prefetch with counted vmcnt (never 0 in steady state), one raw
// s_barrier per half-stage, XOR bank-swizzle via pre-swizzled global source.
//
// lA: 4 half-bufs x [128 rows][32 k] = 16384 shorts; lB: 4 x [64][32] = 8192.
// Swizzle: physical 8-short slot sp within a row holds logical slot
// sp ^ ((row>>1)&3).  Staged by swizzling the per-lane GLOBAL source column
// (gl_lds16 dest must stay linear, guide §5 caveat / rule 21); read side uses
// q4x = q4 ^ ((l15>>1)&3).  Post-swizzle conflict = 2-way (free, m136).
__device__ __forceinline__ void gemm_loop_bk64(const short* __restrict__ Ag,
                                               const short* __restrict__ Bg,
                                               short* lA, short* lB,
                                               int w, int l15, int q4,
                                               f32x4 acc[2][4]) {
  const int K = 2048, HS = 64;            // 64 half-stages of BK=32
  const int q4x = q4 ^ ((l15 >> 1) & 3);  // swizzled k-slot for LDS reads

  auto issue = [&](int h) {               // 3 loads/wave per half-stage
    const short* As = Ag + h * 32;
    const short* Bs = Bg + h * 32;
    const int be = h & 3;
    short* a = lA + be * 4096 + w * 512;
    gl_lds16(As, a);                      // A rows [w*16, +16)
    gl_lds16(As + 64 * K, a + 2048);      // A rows +64
    gl_lds16(Bs, lB + be * 2048 + w * 512);
  };
  auto halfstep = [&](int h) {            // 6 ds_read_b128 + 8 MFMA
    const int be = h & 3;
    const short* ap = lA + be * 4096;
    const short* bp = lB + be * 2048;
    short8 af[2], bf[4];
#pragma unroll
    for (int mf = 0; mf < 2; ++mf)
      af[mf] = *(const short8*)(ap + (w * 32 + mf * 16 + l15) * 32 + q4x * 8);
#pragma unroll
    for (int nf = 0; nf < 4; ++nf)
      bf[nf] = *(const short8*)(bp + (nf * 16 + l15) * 32 + q4x * 8);
    __builtin_amdgcn_s_setprio(1);
#pragma unroll
    for (int mf = 0; mf < 2; ++mf)
#pragma unroll
      for (int nf = 0; nf < 4; ++nf)
        acc[mf][nf] = __builtin_amdgcn_mfma_f32_16x16x32_bf16(af[mf], bf[nf], acc[mf][nf], 0, 0, 0);
    __builtin_amdgcn_s_setprio(0);
  };

  issue(0); issue(1); issue(2);           // 9 loads in flight
  // Steady state: wait vmcnt(6) -> half-stage h landed (h+1,h+2 in flight);
  // barrier -> every wave's h-writes landed AND every wave finished reading
  // buffer (h-1)&3, so issuing h+3 into that buffer after the barrier is safe.
  for (int h = 0; h < HS - 3; ++h) {
    asm volatile("s_waitcnt vmcnt(6)" ::: "memory");
    __builtin_amdgcn_s_barrier();
    asm volatile("" ::: "memory");        // fence: no LDS-read hoist above barrier
    __builtin_amdgcn_sched_barrier(0);
    issue(h + 3);
    halfstep(h);
  }
  // tail: drain 6 -> 3 -> 0
  asm volatile("s_waitcnt vmcnt(6)" ::: "memory");
  __builtin_amdgcn_s_barrier();
  asm volatile("" ::: "memory");
  halfstep(HS - 3);
  asm volatile("s_waitcnt vmcnt(3)" ::: "memory");
  __builtin_amdgcn_s_barrier();
  asm volatile("" ::: "memory");
  halfstep(HS - 2);
  asm volatile("s_waitcnt vmcnt(0)" ::: "memory");
  __builtin_amdgcn_s_barrier();
  asm volatile("" ::: "memory");
  halfstep(HS - 1);
}

// ---------------- fused QKV GEMM + bias + RoPE + scatter epilogue ----------------
__launch_bounds__(256, 3)
__global__ void gemm_qkv(const short* __restrict__ A, const short* __restrict__ BT,
                         const float* __restrict__ bq, const float* __restrict__ bk,
                         const float* __restrict__ bv,
                         short* __restrict__ Qb, short* __restrict__ Kb,
                         short* __restrict__ Vtd) {
  __shared__ __align__(16) short lA[16384];
  __shared__ __align__(16) short lB[8192];
  const int K = 2048;
  const int tid = threadIdx.x, lane = tid & 63, w = tid >> 6;
  const int q4 = lane >> 4, l15 = lane & 15;
  const int bn = blockIdx.x * 64, bm = blockIdx.y * 128;

  // staging source: swizzled k-slot (see gemm_loop_bk64 header comment)
  const int swzc = ((tid & 3) ^ ((tid >> 3) & 3)) << 3;
  const short* Ag = A + (size_t)(bm + (tid >> 2)) * K + swzc;
  const short* Bg = BT + (size_t)(bn + (tid >> 2)) * K + swzc;

  f32x4 acc[2][4];
  const f32x4 fz = {0.f, 0.f, 0.f, 0.f};
#pragma unroll
  for (int i = 0; i < 2; ++i)
#pragma unroll
    for (int j = 0; j < 4; ++j) acc[i][j] = fz;

  gemm_loop_bk64(Ag, Bg, lA, lB, w, l15, q4, acc);

  // ----- epilogue -----
  const float L2T = 0.4152410118609203f;          // log2(10000)/32
  const float theta_a = exp2_fast(-(float)l15 * L2T);
  const float theta_b = exp2_fast(-(float)(l15 + 16) * L2T);
  const float s2 = 0.18033688011112042f;          // 0.125 * log2(e): base-2 attn scores

  if (bn < 2048) {            // ---- Q: rope + scale -> Qb (b,h,t,64)
    const int h = bn >> 6;
    float bb0 = bq[bn + l15], bb1 = bq[bn + 16 + l15], bb2 = bq[bn + 32 + l15], bb3 = bq[bn + 48 + l15];
#pragma unroll
    for (int mf = 0; mf < 2; ++mf)
#pragma unroll
      for (int r = 0; r < 4; ++r) {
        int row = bm + w * 32 + mf * 16 + q4 * 4 + r;
        int batch = row >> 10, t = row & 1023;
        float pos = (float)(t + 1);
        float sa, ca, sb, cb;
        __sincosf(pos * theta_a, &sa, &ca);
        __sincosf(pos * theta_b, &sb, &cb);
        float x0 = acc[mf][0][r] + bb0, x2 = acc[mf][2][r] + bb2;
        float x1 = acc[mf][1][r] + bb1, x3 = acc[mf][3][r] + bb3;
        size_t base = ((size_t)(batch * 32 + h) * 1024 + t) * 64;
        Qb[base + l15]      = f2b((x0 * ca - x2 * sa) * s2);
        Qb[base + l15 + 32] = f2b((x2 * ca + x0 * sa) * s2);
        Qb[base + l15 + 16] = f2b((x1 * cb - x3 * sb) * s2);
        Qb[base + l15 + 48] = f2b((x3 * cb + x1 * sb) * s2);
      }
  } else if (bn < 2560) {     // ---- K: rope -> Kb (b,hkv)[dhalf][t][32]
    const int co = bn - 2048;
    const int hkv = co >> 6;
    float bb0 = bk[co + l15], bb1 = bk[co + 16 + l15], bb2 = bk[co + 32 + l15], bb3 = bk[co + 48 + l15];
#pragma unroll
    for (int mf = 0; mf < 2; ++mf)
#pragma unroll
      for (int r = 0; r < 4; ++r) {
        int row = bm + w * 32 + mf * 16 + q4 * 4 + r;
        int batch = row >> 10, t = row & 1023;
        float pos = (float)(t + 1);
        float sa, ca, sb, cb;
        __sincosf(pos * theta_a, &sa, &ca);
        __sincosf(pos * theta_b, &sb, &cb);
        float x0 = acc[mf][0][r] + bb0, x2 = acc[mf][2][r] + bb2;
        float x1 = acc[mf][1][r] + bb1, x3 = acc[mf][3][r] + bb3;
        size_t base = (size_t)(batch * 8 + hkv) * 65536 + t * 32;
        Kb[base + l15]              = f2b(x0 * ca - x2 * sa);  // d=l15      (half0)
        Kb[base + l15 + 16]         = f2b(x1 * cb - x3 * sb);  // d=l15+16   (half0)
        Kb[base + 32768 + l15]      = f2b(x2 * ca + x0 * sa);  // d=l15+32   (half1)
        Kb[base + 32768 + l15 + 16] = f2b(x3 * cb + x1 * sb);  // d=l15+48   (half1)
      }
  } else {                    // ---- V: bias -> Vtd (b,hkv,t,64)
    const int co = bn - 2560;
    const int hkv = co >> 6;
    float bb[4];
#pragma unroll
    for (int nf = 0; nf < 4; ++nf) bb[nf] = bv[co + nf * 16 + l15];
#pragma unroll
    for (int mf = 0; mf < 2; ++mf)
#pragma unroll
      for (int r = 0; r < 4; ++r) {
        int row = bm + w * 32 + mf * 16 + q4 * 4 + r;
        int batch = row >> 10, t = row & 1023;
        size_t base = (size_t)(batch * 8 + hkv) * 65536 + (size_t)t * 64;
#pragma unroll
        for (int nf = 0; nf < 4; ++nf)
          Vtd[base + nf * 16 + l15] = f2b(acc[mf][nf][r] + bb[nf]);
      }
  }
}

// ---------------- V (b,hkv,t,64) -> VT panels (b,hkv)[tchunk32][d64][32] ----------------
__global__ void vtrans2_kernel(const short* __restrict__ Vtd, short* __restrict__ VTb) {
  __shared__ short tile[64][72];
  const int tt = blockIdx.x, h = blockIdx.y, b = blockIdx.z;
  const int tid = threadIdx.x;
  const size_t base = (size_t)(b * 8 + h) * 65536;
#pragma unroll
  for (int p = 0; p < 2; ++p) {
    int r = (tid >> 3) + p * 32;         // t-local
    int c0 = (tid & 7) * 8;              // d
    short8 v = *(const short8*)(Vtd + base + (size_t)(tt * 64 + r) * 64 + c0);
#pragma unroll
    for (int j = 0; j < 8; ++j) tile[c0 + j][r] = v[j];
  }
  __syncthreads();
  const int d = tid >> 2, ts = (tid & 3) * 8;
#pragma unroll
  for (int tc = 0; tc < 2; ++tc) {
    short8 v = *(const short8*)(&tile[d][tc * 32 + ts]);
    *(short8*)(VTb + base + (size_t)(tt * 2 + tc) * 2048 + d * 32 + ts) = v;
  }
}

// ---------------- flash attention v5: block-cooperative LDS staging ----------------
// grid (8, 32, B); block = 128 q-rows; wave w owns rows [qt*128+w*32, +32).
// Per stage: 128 k-cols of K and V^T staged to LDS (8x global_load_lds), 2-barrier loop.
// Fixed-shift softmax P=2^(s2-16) (state is linear, no running max).
// NEW: same T2 swizzle as the GEMMs on the K/V LDS tiles (pre-swizzled global
// source + q4x read slot) to kill the 8-way ds_read_b128 bank conflict.
#define PROW 72
__launch_bounds__(256, 3)
__global__ void attn5_kernel(const short* __restrict__ Qb, const short* __restrict__ Kb,
                             const short* __restrict__ VTb, short* __restrict__ AO) {
  __shared__ __align__(16) short lK[2][128 * 32];    // [dhalf][krow][32]
  __shared__ __align__(16) short lVT[4][64 * 32];    // [tchunk][d][32]
  __shared__ __align__(16) short lP[4][2][16 * PROW];
  const int tid = threadIdx.x, lane = tid & 63, w = tid >> 6;
  const int q4 = lane >> 4, l15 = lane & 15;
  const int q4x = q4 ^ ((l15 >> 1) & 3);             // swizzled k-slot for LDS reads
  const int swzc = ((tid & 3) ^ ((tid >> 3) & 3)) << 3;  // swizzled staging source col
  const int qt = (int)gridDim.x - 1 - (int)blockIdx.x;  // heavy blocks first
  const int h = blockIdx.y, b = blockIdx.z;
  const int hkv = h >> 2;
  const int qb = qt * 128 + w * 32;
  const int kdiag = qb >> 6;            // wave's diagonal 64-tile
  const int ns = qt + 1;                // stages of 128 k-cols

  const short* Qg = Qb + (size_t)(b * 32 + h) * 65536;
  const short* Kg = Kb + (size_t)(b * 8 + hkv) * 65536;
  const short* Vg = VTb + (size_t)(b * 8 + hkv) * 65536;

  short8 qf[2][2];
#pragma unroll
  for (int mf = 0; mf < 2; ++mf) {
    const short* qr = Qg + (size_t)(qb + mf * 16 + l15) * 64 + q4 * 8;
    qf[mf][0] = *(const short8*)(qr);
    qf[mf][1] = *(const short8*)(qr + 32);
  }

  const f32x4 fz = {0.f, 0.f, 0.f, 0.f};
  f32x4 o[2][4], ol[2];
#pragma unroll
  for (int mf = 0; mf < 2; ++mf) {
    ol[mf] = fz;
#pragma unroll
    for (int i = 0; i < 4; ++i) o[mf][i] = fz;
  }
  short8 ones;
#pragma unroll
  for (int i = 0; i < 8; ++i) ones[i] = (short)0x3F80;

  for (int s = 0; s < ns; ++s) {
    {
      const short* Ksrc = Kg + (size_t)(s * 128 + (tid >> 2)) * 32 + swzc;
      short* ldst = (short*)lK + w * 512;
      gl_lds16(Ksrc, ldst);
      gl_lds16(Ksrc + 64 * 32, ldst + 2048);
      gl_lds16(Ksrc + 32768, ldst + 4096);
      gl_lds16(Ksrc + 32768 + 64 * 32, ldst + 6144);
      const short* Vsrc = Vg + (size_t)(s * 4) * 2048 + (tid >> 2) * 32 + swzc;
      short* vdst = (short*)lVT + w * 512;
#pragma unroll
      for (int c = 0; c < 4; ++c) gl_lds16(Vsrc + c * 2048, vdst + c * 2048);
    }
    __syncthreads();

#pragma unroll
    for (int ki = 0; ki < 2; ++ki) {
      const int ktg = s * 2 + ki;
      if (ktg <= kdiag) {
        short8 kf0[4], kf1[4];
#pragma unroll
        for (int nt = 0; nt < 4; ++nt) {
          kf0[nt] = *(const short8*)((short*)lK + (ki * 64 + nt * 16 + l15) * 32 + q4x * 8);
          kf1[nt] = *(const short8*)((short*)lK + 4096 + (ki * 64 + nt * 16 + l15) * 32 + q4x * 8);
        }
        const bool diag = (ktg == kdiag);
#pragma unroll
        for (int mf = 0; mf < 2; ++mf) {
          f32x4 sv[4];
#pragma unroll
          for (int nt = 0; nt < 4; ++nt) {
            f32x4 z = __builtin_amdgcn_mfma_f32_16x16x32_bf16(qf[mf][0], kf0[nt], fz, 0, 0, 0);
            sv[nt] = __builtin_amdgcn_mfma_f32_16x16x32_bf16(qf[mf][1], kf1[nt], z, 0, 0, 0);
          }
          if (diag) {
#pragma unroll
            for (int r = 0; r < 4; ++r) {
              const int qrow = qb + mf * 16 + q4 * 4 + r;
              const int col = ktg * 64 + l15;
#pragma unroll
              for (int nt = 0; nt < 4; ++nt)
                if (col + nt * 16 > qrow) sv[nt][r] = -1e30f;
            }
          }
          short* lPm = lP[w][mf];
#pragma unroll
          for (int r = 0; r < 4; ++r)
#pragma unroll
            for (int nt = 0; nt < 4; ++nt)
              lPm[(q4 * 4 + r) * PROW + nt * 16 + l15] = f2b(exp2_fast(sv[nt][r] - 16.f));
        }

        short8 vf0[4], vf1[4];
#pragma unroll
        for (int dt = 0; dt < 4; ++dt) {
          vf0[dt] = *(const short8*)((short*)lVT + (2 * ki) * 2048 + (dt * 16 + l15) * 32 + q4x * 8);
          vf1[dt] = *(const short8*)((short*)lVT + (2 * ki + 1) * 2048 + (dt * 16 + l15) * 32 + q4x * 8);
        }
#pragma unroll
        for (int mf = 0; mf < 2; ++mf) {
          const short* lPm = lP[w][mf];
          short8 pf0 = *(const short8*)(lPm + l15 * PROW + q4 * 8);
          short8 pf1 = *(const short8*)(lPm + l15 * PROW + 32 + q4 * 8);
          ol[mf] = __builtin_amdgcn_mfma_f32_16x16x32_bf16(pf0, ones, ol[mf], 0, 0, 0);
          ol[mf] = __builtin_amdgcn_mfma_f32_16x16x32_bf16(pf1, ones, ol[mf], 0, 0, 0);
#pragma unroll
          for (int dt = 0; dt < 4; ++dt) {
            o[mf][dt] = __builtin_amdgcn_mfma_f32_16x16x32_bf16(pf0, vf0[dt], o[mf][dt], 0, 0, 0);
            o[mf][dt] = __builtin_amdgcn_mfma_f32_16x16x32_bf16(pf1, vf1[dt], o[mf][dt], 0, 0, 0);
          }
        }
      }
    }
    __syncthreads();
  }

#pragma unroll
  for (int mf = 0; mf < 2; ++mf)
#pragma unroll
    for (int r = 0; r < 4; ++r) {
      float inv = __builtin_amdgcn_rcpf(ol[mf][r]);
      int row = qb + mf * 16 + q4 * 4 + r;
#pragma unroll
      for (int dt = 0; dt < 4; ++dt)
        AO[(size_t)(b * 1024 + row) * 2048 + h * 64 + dt * 16 + l15] = f2b(o[mf][dt][r] * inv);
    }
}

// ---------------- output projection: pipelined K-loop, fp32 out + bias ----------------
__launch_bounds__(256, 3)
__global__ void gemm_out(const short* __restrict__ A, const short* __restrict__ BT,
                         float* __restrict__ C, const float* __restrict__ bias,
                         int N, int K) {
  __shared__ __align__(16) short lA[16384];
  __shared__ __align__(16) short lB[8192];
  const int tid = threadIdx.x, lane = tid & 63, w = tid >> 6;
  const int q4 = lane >> 4, l15 = lane & 15;
  const int bn = blockIdx.x * 64, bm = blockIdx.y * 128;

  const int swzc = ((tid & 3) ^ ((tid >> 3) & 3)) << 3;
  const short* Ag = A + (size_t)(bm + (tid >> 2)) * K + swzc;
  const short* Bg = BT + (size_t)(bn + (tid >> 2)) * K + swzc;

  f32x4 acc[2][4];
  const f32x4 fz = {0.f, 0.f, 0.f, 0.f};
#pragma unroll
  for (int i = 0; i < 2; ++i)
#pragma unroll
    for (int j = 0; j < 4; ++j) acc[i][j] = fz;

  gemm_loop_bk64(Ag, Bg, lA, lB, w, l15, q4, acc);

#pragma unroll
  for (int mf = 0; mf < 2; ++mf)
#pragma unroll
    for (int nf = 0; nf < 4; ++nf) {
      int col = bn + nf * 16 + l15;
      float bb = bias[col];
#pragma unroll
      for (int r = 0; r < 4; ++r) {
        int row = bm + w * 32 + mf * 16 + q4 * 4 + r;
        C[(size_t)row * N + col] = acc[mf][nf][r] + bb;
      }
    }
}

extern "C" void kernel_launch(void* const* d_in, const int* in_sizes, int n_in,
                              void* d_out, int out_size, void* d_ws, size_t ws_size,
                              hipStream_t stream) {
  const float* x  = (const float*)d_in[0];
  const float* wq = (const float*)d_in[1];
  const float* bq = (const float*)d_in[2];
  const float* wk = (const float*)d_in[3];
  const float* bk = (const float*)d_in[4];
  const float* wv = (const float*)d_in[5];
  const float* bv = (const float*)d_in[6];
  const float* wo = (const float*)d_in[7];
  const float* bo = (const float*)d_in[8];
  float* out = (float*)d_out;
  const int B = in_sizes[0] / (1024 * 2048);
  const int M = B * 1024;

  char* ws = (char*)d_ws;
  size_t off = 0;
  auto alloc = [&](size_t bytes) -> char* {
    char* p = ws + off;
    off += (bytes + 255) & ~(size_t)255;
    return p;
  };
  short* xb    = (short*)alloc((size_t)M * 2048 * 2);
  short* WqkvT = (short*)alloc((size_t)3072 * 2048 * 2);  // rows: wq^T | wk^T | wv^T (K-major)
  short* woT   = (short*)alloc((size_t)2048 * 2048 * 2);
  short* Qb    = (short*)alloc((size_t)B * 32 * 1024 * 64 * 2);    // (b,h,t,d)
  short* Kb    = (short*)alloc((size_t)B * 8 * 2 * 1024 * 32 * 2); // (b,hkv)[dhalf][t][32]
  short* Vtd   = (short*)alloc((size_t)B * 8 * 1024 * 64 * 2);     // (b,hkv,t,d)
  short* VTb   = (short*)alloc((size_t)B * 8 * 32 * 64 * 32 * 2);  // (b,hkv)[tchunk][d][32]
  short* AO    = (short*)alloc((size_t)M * 2048 * 2);              // (b,t,E) bf16

  cast_x_kernel<<<(M * 2048 / 4 + 255) / 256, 256, 0, stream>>>(x, xb, M * 2048 / 4);
  wtrans_all<<<dim3(80, 32), 256, 0, stream>>>(wq, wk, wv, wo, WqkvT, woT);
  gemm_qkv<<<dim3(48, M / 128), 256, 0, stream>>>(xb, WqkvT, bq, bk, bv, Qb, Kb, Vtd);
  vtrans2_kernel<<<dim3(16, 8, B), 256, 0, stream>>>(Vtd, VTb);
  attn5_kernel<<<dim3(8, 32, B), 256, 0, stream>>>(Qb, Kb, VTb, AO);
  gemm_out<<<dim3(32, M / 128), 256, 0, stream>>>(AO, woT, out, bo, 2048, 2048);
}

// Round 2
// 225.672 us; speedup vs baseline: 1.0028x; 1.0028x over previous
//
#include <hip/hip_runtime.h>
#include <hip/hip_bf16.h>
#include <cstdint>

// GQA prefill: b=2, t=1024, E=2048, NQ=32, NKV=8, HD=64. fp32 in/out, bf16 MFMA inside.

typedef __attribute__((ext_vector_type(8))) short short8;   // 8 bf16 (MFMA A/B frag)
typedef __attribute__((ext_vector_type(4))) short short4v;
typedef __attribute__((ext_vector_type(4))) float f32x4;    // MFMA C/D frag

__device__ inline short f2b(float f) {  // fp32 -> bf16 (RNE)
  union { float f; unsigned u; } v; v.f = f;
  unsigned r = v.u + 0x7fffu + ((v.u >> 16) & 1u);
  return (short)(r >> 16);
}

__device__ inline float exp2_fast(float x) {
  float r;
  asm("v_exp_f32 %0, %1" : "=v"(r) : "v"(x));
  return r;
}

__device__ inline void gl_lds16(const void* g, void* l) {
  // async global->LDS, 16B/lane; LDS dest = wave-uniform base + lane*16
  __builtin_amdgcn_global_load_lds((const __attribute__((address_space(1))) void*)g,
                                   (__attribute__((address_space(3))) void*)l,
                                   16, 0, 0);
}

// ---------------- elementwise cast x -> bf16 ----------------
__global__ void cast_x_kernel(const float* __restrict__ x, short* __restrict__ xb, int n4) {
  int i = blockIdx.x * 256 + threadIdx.x;
  if (i >= n4) return;
  float4 v = ((const float4*)x)[i];
  short4v o; o.x = f2b(v.x); o.y = f2b(v.y); o.z = f2b(v.z); o.w = f2b(v.w);
  ((short4v*)xb)[i] = o;
}

// ---------------- all weight transposes in one launch ----------------
// grid (80, 32): x<32 wq | <40 wk | <48 wv | else wo. 64x64 LDS tile each.
__global__ void wtrans_all(const float* __restrict__ wq, const float* __restrict__ wk,
                           const float* __restrict__ wv, const float* __restrict__ wo,
                           short* __restrict__ WqkvT, short* __restrict__ woT) {
  __shared__ float tile[64][65];
  const int bx = blockIdx.x;
  const float* W; short* WT; int N, off, nb;
  if (bx < 32)      { W = wq; WT = WqkvT; N = 2048; off = 0;    nb = bx * 64; }
  else if (bx < 40) { W = wk; WT = WqkvT; N = 512;  off = 2048; nb = (bx - 32) * 64; }
  else if (bx < 48) { W = wv; WT = WqkvT; N = 512;  off = 2560; nb = (bx - 40) * 64; }
  else              { W = wo; WT = woT;   N = 2048; off = 0;    nb = (bx - 48) * 64; }
  const int kb = blockIdx.y * 64;
  const int tid = threadIdx.x;
  const int c = tid & 63, r0 = tid >> 6;
#pragma unroll
  for (int s = 0; s < 16; ++s) {
    int k = r0 + s * 4;
    tile[c][k] = W[(size_t)(kb + k) * N + nb + c];
  }
  __syncthreads();
#pragma unroll
  for (int s = 0; s < 16; ++s) {
    int n = r0 + s * 4;
    WT[(size_t)(off + nb + n) * 2048 + kb + c] = f2b(tile[n][c]);
  }
}

// ---------------- shared K-loop: 128(M)x128(N) tile, K=2048, BK=32, dbuf ----------------
// m97-geometry: 4 waves in a 2x2 grid, each wave owns a 64x64 output (acc[4][4]).
// Per stage (BK=32): per wave 4 gl_lds (A rows j*64, B rows j*64) + 8 ds_read_b128
// + 16 MFMA; one __syncthreads per stage (implicit vmcnt drain = the proven
// m97 874-TF structure).  LDS 32KB total: lA[2][128][32], lB[2][128][32].
// T2 swizzle (verified R1, conflicts 4.7M->0): LDS stays linear; GLOBAL source
// column is pre-swizzled (slot ^= (row>>1)&3 -> swzc), reads use q4x.
__device__ __forceinline__ void gemm_loop_128(const short* __restrict__ Ag,
                                              const short* __restrict__ Bg,
                                              short* lA, short* lB,
                                              int w, int wr, int wc, int l15, int q4,
                                              f32x4 acc[4][4]) {
  const int K = 2048, NS = 64;            // 64 stages of BK=32
  const int q4x = q4 ^ ((l15 >> 1) & 3);  // swizzled k-slot for LDS reads

  auto stage = [&](int s, int d) {        // 4 loads/wave per stage
    const short* As = Ag + s * 32;
    const short* Bs = Bg + s * 32;
    gl_lds16(As,          lA + d * 4096 + w * 512);          // A rows [0,64)
    gl_lds16(As + 64 * K, lA + d * 4096 + 2048 + w * 512);   // A rows [64,128)
    gl_lds16(Bs,          lB + d * 4096 + w * 512);          // B rows [0,64)
    gl_lds16(Bs + 64 * K, lB + d * 4096 + 2048 + w * 512);   // B rows [64,128)
  };

  stage(0, 0);
  for (int s = 0; s < NS; ++s) {
    const int d = s & 1;
    __syncthreads();                      // drains stage(s) loads; frees buf d^1
    if (s + 1 < NS) stage(s + 1, d ^ 1);  // prefetch next stage
    const short* ap = lA + d * 4096;
    const short* bp = lB + d * 4096;
    short8 af[4], bf[4];
#pragma unroll
    for (int mi = 0; mi < 4; ++mi)
      af[mi] = *(const short8*)(ap + (wr * 64 + mi * 16 + l15) * 32 + q4x * 8);
#pragma unroll
    for (int ni = 0; ni < 4; ++ni)
      bf[ni] = *(const short8*)(bp + (wc * 64 + ni * 16 + l15) * 32 + q4x * 8);
#pragma unroll
    for (int mi = 0; mi < 4; ++mi)
#pragma unroll
      for (int ni = 0; ni < 4; ++ni)
        acc[mi][ni] = __builtin_amdgcn_mfma_f32_16x16x32_bf16(af[mi], bf[ni], acc[mi][ni], 0, 0, 0);
  }
}

// ---------------- fused QKV GEMM + bias + RoPE + scatter epilogue ----------------
// grid (24, M/128): bn = bx*128.  Q: bn<2048 | K: <2560 | V: else.
// Each wave's 64 output cols land on exactly one head (cb = bn + wc*64).
__launch_bounds__(256, 3)
__global__ void gemm_qkv(const short* __restrict__ A, const short* __restrict__ BT,
                         const float* __restrict__ bq, const float* __restrict__ bk,
                         const float* __restrict__ bv,
                         short* __restrict__ Qb, short* __restrict__ Kb,
                         short* __restrict__ Vtd) {
  __shared__ __align__(16) short lA[8192];
  __shared__ __align__(16) short lB[8192];
  const int K = 2048;
  const int tid = threadIdx.x, lane = tid & 63, w = tid >> 6;
  const int wr = w >> 1, wc = w & 1;
  const int q4 = lane >> 4, l15 = lane & 15;
  const int bn = blockIdx.x * 128, bm = blockIdx.y * 128;

  // staging source: swizzled k-slot (see gemm_loop_128 header comment)
  const int swzc = ((tid & 3) ^ ((tid >> 3) & 3)) << 3;
  const short* Ag = A + (size_t)(bm + (tid >> 2)) * K + swzc;
  const short* Bg = BT + (size_t)(bn + (tid >> 2)) * K + swzc;

  f32x4 acc[4][4];
  const f32x4 fz = {0.f, 0.f, 0.f, 0.f};
#pragma unroll
  for (int i = 0; i < 4; ++i)
#pragma unroll
    for (int j = 0; j < 4; ++j) acc[i][j] = fz;

  gemm_loop_128(Ag, Bg, lA, lB, w, wr, wc, l15, q4, acc);

  // ----- epilogue -----
  const float L2T = 0.4152410118609203f;          // log2(10000)/32
  const float theta_a = exp2_fast(-(float)l15 * L2T);
  const float theta_b = exp2_fast(-(float)(l15 + 16) * L2T);
  const float s2 = 0.18033688011112042f;          // 0.125 * log2(e): base-2 attn scores
  const int cb = bn + wc * 64;                    // wave's column base (one head)

  if (cb < 2048) {            // ---- Q: rope + scale -> Qb (b,h,t,64)
    const int h = cb >> 6;
    float bb0 = bq[cb + l15], bb1 = bq[cb + 16 + l15], bb2 = bq[cb + 32 + l15], bb3 = bq[cb + 48 + l15];
#pragma unroll
    for (int mi = 0; mi < 4; ++mi)
#pragma unroll
      for (int r = 0; r < 4; ++r) {
        int row = bm + wr * 64 + mi * 16 + q4 * 4 + r;
        int batch = row >> 10, t = row & 1023;
        float pos = (float)(t + 1);
        float sa, ca, sb, cb2;
        __sincosf(pos * theta_a, &sa, &ca);
        __sincosf(pos * theta_b, &sb, &cb2);
        float x0 = acc[mi][0][r] + bb0, x2 = acc[mi][2][r] + bb2;
        float x1 = acc[mi][1][r] + bb1, x3 = acc[mi][3][r] + bb3;
        size_t base = ((size_t)(batch * 32 + h) * 1024 + t) * 64;
        Qb[base + l15]      = f2b((x0 * ca - x2 * sa) * s2);
        Qb[base + l15 + 32] = f2b((x2 * ca + x0 * sa) * s2);
        Qb[base + l15 + 16] = f2b((x1 * cb2 - x3 * sb) * s2);
        Qb[base + l15 + 48] = f2b((x3 * cb2 + x1 * sb) * s2);
      }
  } else if (cb < 2560) {     // ---- K: rope -> Kb (b,hkv)[dhalf][t][32]
    const int co = cb - 2048;
    const int hkv = co >> 6;
    float bb0 = bk[co + l15], bb1 = bk[co + 16 + l15], bb2 = bk[co + 32 + l15], bb3 = bk[co + 48 + l15];
#pragma unroll
    for (int mi = 0; mi < 4; ++mi)
#pragma unroll
      for (int r = 0; r < 4; ++r) {
        int row = bm + wr * 64 + mi * 16 + q4 * 4 + r;
        int batch = row >> 10, t = row & 1023;
        float pos = (float)(t + 1);
        float sa, ca, sb, cb2;
        __sincosf(pos * theta_a, &sa, &ca);
        __sincosf(pos * theta_b, &sb, &cb2);
        float x0 = acc[mi][0][r] + bb0, x2 = acc[mi][2][r] + bb2;
        float x1 = acc[mi][1][r] + bb1, x3 = acc[mi][3][r] + bb3;
        size_t base = (size_t)(batch * 8 + hkv) * 65536 + t * 32;
        Kb[base + l15]              = f2b(x0 * ca - x2 * sa);  // d=l15      (half0)
        Kb[base + l15 + 16]         = f2b(x1 * cb2 - x3 * sb); // d=l15+16   (half0)
        Kb[base + 32768 + l15]      = f2b(x2 * ca + x0 * sa);  // d=l15+32   (half1)
        Kb[base + 32768 + l15 + 16] = f2b(x3 * cb2 + x1 * sb); // d=l15+48   (half1)
      }
  } else {                    // ---- V: bias -> Vtd (b,hkv,t,64)
    const int co = cb - 2560;
    const int hkv = co >> 6;
    float bb[4];
#pragma unroll
    for (int nf = 0; nf < 4; ++nf) bb[nf] = bv[co + nf * 16 + l15];
#pragma unroll
    for (int mi = 0; mi < 4; ++mi)
#pragma unroll
      for (int r = 0; r < 4; ++r) {
        int row = bm + wr * 64 + mi * 16 + q4 * 4 + r;
        int batch = row >> 10, t = row & 1023;
        size_t base = (size_t)(batch * 8 + hkv) * 65536 + (size_t)t * 64;
#pragma unroll
        for (int nf = 0; nf < 4; ++nf)
          Vtd[base + nf * 16 + l15] = f2b(acc[mi][nf][r] + bb[nf]);
      }
  }
}

// ---------------- V (b,hkv,t,64) -> VT panels (b,hkv)[tchunk32][d64][32] ----------------
__global__ void vtrans2_kernel(const short* __restrict__ Vtd, short* __restrict__ VTb) {
  __shared__ short tile[64][72];
  const int tt = blockIdx.x, h = blockIdx.y, b = blockIdx.z;
  const int tid = threadIdx.x;
  const size_t base = (size_t)(b * 8 + h) * 65536;
#pragma unroll
  for (int p = 0; p < 2; ++p) {
    int r = (tid >> 3) + p * 32;         // t-local
    int c0 = (tid & 7) * 8;              // d
    short8 v = *(const short8*)(Vtd + base + (size_t)(tt * 64 + r) * 64 + c0);
#pragma unroll
    for (int j = 0; j < 8; ++j) tile[c0 + j][r] = v[j];
  }
  __syncthreads();
  const int d = tid >> 2, ts = (tid & 3) * 8;
#pragma unroll
  for (int tc = 0; tc < 2; ++tc) {
    short8 v = *(const short8*)(&tile[d][tc * 32 + ts]);
    *(short8*)(VTb + base + (size_t)(tt * 2 + tc) * 2048 + d * 32 + ts) = v;
  }
}

// ---------------- flash attention v5: block-cooperative LDS staging ----------------
// grid (8, 32, B); block = 128 q-rows; wave w owns rows [qt*128+w*32, +32).
// Per stage: 128 k-cols of K and V^T staged to LDS (8x global_load_lds), 2-barrier loop.
// Fixed-shift softmax P=2^(s2-16) (state is linear, no running max).
// T2 swizzle on K/V LDS tiles (pre-swizzled global source + q4x read slot).
#define PROW 72
__launch_bounds__(256, 3)
__global__ void attn5_kernel(const short* __restrict__ Qb, const short* __restrict__ Kb,
                             const short* __restrict__ VTb, short* __restrict__ AO) {
  __shared__ __align__(16) short lK[2][128 * 32];    // [dhalf][krow][32]
  __shared__ __align__(16) short lVT[4][64 * 32];    // [tchunk][d][32]
  __shared__ __align__(16) short lP[4][2][16 * PROW];
  const int tid = threadIdx.x, lane = tid & 63, w = tid >> 6;
  const int q4 = lane >> 4, l15 = lane & 15;
  const int q4x = q4 ^ ((l15 >> 1) & 3);             // swizzled k-slot for LDS reads
  const int swzc = ((tid & 3) ^ ((tid >> 3) & 3)) << 3;  // swizzled staging source col
  const int qt = (int)gridDim.x - 1 - (int)blockIdx.x;  // heavy blocks first
  const int h = blockIdx.y, b = blockIdx.z;
  const int hkv = h >> 2;
  const int qb = qt * 128 + w * 32;
  const int kdiag = qb >> 6;            // wave's diagonal 64-tile
  const int ns = qt + 1;                // stages of 128 k-cols

  const short* Qg = Qb + (size_t)(b * 32 + h) * 65536;
  const short* Kg = Kb + (size_t)(b * 8 + hkv) * 65536;
  const short* Vg = VTb + (size_t)(b * 8 + hkv) * 65536;

  short8 qf[2][2];
#pragma unroll
  for (int mf = 0; mf < 2; ++mf) {
    const short* qr = Qg + (size_t)(qb + mf * 16 + l15) * 64 + q4 * 8;
    qf[mf][0] = *(const short8*)(qr);
    qf[mf][1] = *(const short8*)(qr + 32);
  }

  const f32x4 fz = {0.f, 0.f, 0.f, 0.f};
  f32x4 o[2][4], ol[2];
#pragma unroll
  for (int mf = 0; mf < 2; ++mf) {
    ol[mf] = fz;
#pragma unroll
    for (int i = 0; i < 4; ++i) o[mf][i] = fz;
  }
  short8 ones;
#pragma unroll
  for (int i = 0; i < 8; ++i) ones[i] = (short)0x3F80;

  for (int s = 0; s < ns; ++s) {
    {
      const short* Ksrc = Kg + (size_t)(s * 128 + (tid >> 2)) * 32 + swzc;
      short* ldst = (short*)lK + w * 512;
      gl_lds16(Ksrc, ldst);
      gl_lds16(Ksrc + 64 * 32, ldst + 2048);
      gl_lds16(Ksrc + 32768, ldst + 4096);
      gl_lds16(Ksrc + 32768 + 64 * 32, ldst + 6144);
      const short* Vsrc = Vg + (size_t)(s * 4) * 2048 + (tid >> 2) * 32 + swzc;
      short* vdst = (short*)lVT + w * 512;
#pragma unroll
      for (int c = 0; c < 4; ++c) gl_lds16(Vsrc + c * 2048, vdst + c * 2048);
    }
    __syncthreads();

#pragma unroll
    for (int ki = 0; ki < 2; ++ki) {
      const int ktg = s * 2 + ki;
      if (ktg <= kdiag) {
        short8 kf0[4], kf1[4];
#pragma unroll
        for (int nt = 0; nt < 4; ++nt) {
          kf0[nt] = *(const short8*)((short*)lK + (ki * 64 + nt * 16 + l15) * 32 + q4x * 8);
          kf1[nt] = *(const short8*)((short*)lK + 4096 + (ki * 64 + nt * 16 + l15) * 32 + q4x * 8);
        }
        const bool diag = (ktg == kdiag);
#pragma unroll
        for (int mf = 0; mf < 2; ++mf) {
          f32x4 sv[4];
#pragma unroll
          for (int nt = 0; nt < 4; ++nt) {
            f32x4 z = __builtin_amdgcn_mfma_f32_16x16x32_bf16(qf[mf][0], kf0[nt], fz, 0, 0, 0);
            sv[nt] = __builtin_amdgcn_mfma_f32_16x16x32_bf16(qf[mf][1], kf1[nt], z, 0, 0, 0);
          }
          if (diag) {
#pragma unroll
            for (int r = 0; r < 4; ++r) {
              const int qrow = qb + mf * 16 + q4 * 4 + r;
              const int col = ktg * 64 + l15;
#pragma unroll
              for (int nt = 0; nt < 4; ++nt)
                if (col + nt * 16 > qrow) sv[nt][r] = -1e30f;
            }
          }
          short* lPm = lP[w][mf];
#pragma unroll
          for (int r = 0; r < 4; ++r)
#pragma unroll
            for (int nt = 0; nt < 4; ++nt)
              lPm[(q4 * 4 + r) * PROW + nt * 16 + l15] = f2b(exp2_fast(sv[nt][r] - 16.f));
        }

        short8 vf0[4], vf1[4];
#pragma unroll
        for (int dt = 0; dt < 4; ++dt) {
          vf0[dt] = *(const short8*)((short*)lVT + (2 * ki) * 2048 + (dt * 16 + l15) * 32 + q4x * 8);
          vf1[dt] = *(const short8*)((short*)lVT + (2 * ki + 1) * 2048 + (dt * 16 + l15) * 32 + q4x * 8);
        }
#pragma unroll
        for (int mf = 0; mf < 2; ++mf) {
          const short* lPm = lP[w][mf];
          short8 pf0 = *(const short8*)(lPm + l15 * PROW + q4 * 8);
          short8 pf1 = *(const short8*)(lPm + l15 * PROW + 32 + q4 * 8);
          ol[mf] = __builtin_amdgcn_mfma_f32_16x16x32_bf16(pf0, ones, ol[mf], 0, 0, 0);
          ol[mf] = __builtin_amdgcn_mfma_f32_16x16x32_bf16(pf1, ones, ol[mf], 0, 0, 0);
#pragma unroll
          for (int dt = 0; dt < 4; ++dt) {
            o[mf][dt] = __builtin_amdgcn_mfma_f32_16x16x32_bf16(pf0, vf0[dt], o[mf][dt], 0, 0, 0);
            o[mf][dt] = __builtin_amdgcn_mfma_f32_16x16x32_bf16(pf1, vf1[dt], o[mf][dt], 0, 0, 0);
          }
        }
      }
    }
    __syncthreads();
  }

#pragma unroll
  for (int mf = 0; mf < 2; ++mf)
#pragma unroll
    for (int r = 0; r < 4; ++r) {
      float inv = __builtin_amdgcn_rcpf(ol[mf][r]);
      int row = qb + mf * 16 + q4 * 4 + r;
#pragma unroll
      for (int dt = 0; dt < 4; ++dt)
        AO[(size_t)(b * 1024 + row) * 2048 + h * 64 + dt * 16 + l15] = f2b(o[mf][dt][r] * inv);
    }
}

// ---------------- output projection: 128x128 tile, fp32 out + bias ----------------
__launch_bounds__(256, 3)
__global__ void gemm_out(const short* __restrict__ A, const short* __restrict__ BT,
                         float* __restrict__ C, const float* __restrict__ bias,
                         int N, int K) {
  __shared__ __align__(16) short lA[8192];
  __shared__ __align__(16) short lB[8192];
  const int tid = threadIdx.x, lane = tid & 63, w = tid >> 6;
  const int wr = w >> 1, wc = w & 1;
  const int q4 = lane >> 4, l15 = lane & 15;
  const int bn = blockIdx.x * 128, bm = blockIdx.y * 128;

  const int swzc = ((tid & 3) ^ ((tid >> 3) & 3)) << 3;
  const short* Ag = A + (size_t)(bm + (tid >> 2)) * K + swzc;
  const short* Bg = BT + (size_t)(bn + (tid >> 2)) * K + swzc;

  f32x4 acc[4][4];
  const f32x4 fz = {0.f, 0.f, 0.f, 0.f};
#pragma unroll
  for (int i = 0; i < 4; ++i)
#pragma unroll
    for (int j = 0; j < 4; ++j) acc[i][j] = fz;

  gemm_loop_128(Ag, Bg, lA, lB, w, wr, wc, l15, q4, acc);

#pragma unroll
  for (int mi = 0; mi < 4; ++mi)
#pragma unroll
    for (int ni = 0; ni < 4; ++ni) {
      int col = bn + wc * 64 + ni * 16 + l15;
      float bb = bias[col];
#pragma unroll
      for (int r = 0; r < 4; ++r) {
        int row = bm + wr * 64 + mi * 16 + q4 * 4 + r;
        C[(size_t)row * N + col] = acc[mi][ni][r] + bb;
      }
    }
}

extern "C" void kernel_launch(void* const* d_in, const int* in_sizes, int n_in,
                              void* d_out, int out_size, void* d_ws, size_t ws_size,
                              hipStream_t stream) {
  const float* x  = (const float*)d_in[0];
  const float* wq = (const float*)d_in[1];
  const float* bq = (const float*)d_in[2];
  const float* wk = (const float*)d_in[3];
  const float* bk = (const float*)d_in[4];
  const float* wv = (const float*)d_in[5];
  const float* bv = (const float*)d_in[6];
  const float* wo = (const float*)d_in[7];
  const float* bo = (const float*)d_in[8];
  float* out = (float*)d_out;
  const int B = in_sizes[0] / (1024 * 2048);
  const int M = B * 1024;

  char* ws = (char*)d_ws;
  size_t off = 0;
  auto alloc = [&](size_t bytes) -> char* {
    char* p = ws + off;
    off += (bytes + 255) & ~(size_t)255;
    return p;
  };
  short* xb    = (short*)alloc((size_t)M * 2048 * 2);
  short* WqkvT = (short*)alloc((size_t)3072 * 2048 * 2);  // rows: wq^T | wk^T | wv^T (K-major)
  short* woT   = (short*)alloc((size_t)2048 * 2048 * 2);
  short* Qb    = (short*)alloc((size_t)B * 32 * 1024 * 64 * 2);    // (b,h,t,d)
  short* Kb    = (short*)alloc((size_t)B * 8 * 2 * 1024 * 32 * 2); // (b,hkv)[dhalf][t][32]
  short* Vtd   = (short*)alloc((size_t)B * 8 * 1024 * 64 * 2);     // (b,hkv,t,d)
  short* VTb   = (short*)alloc((size_t)B * 8 * 32 * 64 * 32 * 2);  // (b,hkv)[tchunk][d][32]
  short* AO    = (short*)alloc((size_t)M * 2048 * 2);              // (b,t,E) bf16

  cast_x_kernel<<<(M * 2048 / 4 + 255) / 256, 256, 0, stream>>>(x, xb, M * 2048 / 4);
  wtrans_all<<<dim3(80, 32), 256, 0, stream>>>(wq, wk, wv, wo, WqkvT, woT);
  gemm_qkv<<<dim3(24, M / 128), 256, 0, stream>>>(xb, WqkvT, bq, bk, bv, Qb, Kb, Vtd);
  vtrans2_kernel<<<dim3(16, 8, B), 256, 0, stream>>>(Vtd, VTb);
  attn5_kernel<<<dim3(8, 32, B), 256, 0, stream>>>(Qb, Kb, VTb, AO);
  gemm_out<<<dim3(16, M / 128), 256, 0, stream>>>(AO, woT, out, bo, 2048, 2048);
}

// Round 3
// 206.164 us; speedup vs baseline: 1.0977x; 1.0946x over previous
//
#include <hip/hip_runtime.h>
#include <hip/hip_bf16.h>
#include <cstdint>

// GQA prefill: b=2, t=1024, E=2048, NQ=32, NKV=8, HD=64. fp32 in/out, bf16 MFMA inside.

typedef __attribute__((ext_vector_type(8))) short short8;   // 8 bf16 (MFMA A/B frag)
typedef __attribute__((ext_vector_type(4))) short short4v;
typedef __attribute__((ext_vector_type(4))) float f32x4;    // MFMA C/D frag

__device__ inline short f2b(float f) {  // fp32 -> bf16 (RNE)
  union { float f; unsigned u; } v; v.f = f;
  unsigned r = v.u + 0x7fffu + ((v.u >> 16) & 1u);
  return (short)(r >> 16);
}

__device__ inline float exp2_fast(float x) {
  float r;
  asm("v_exp_f32 %0, %1" : "=v"(r) : "v"(x));
  return r;
}

__device__ inline void gl_lds16(const void* g, void* l) {
  // async global->LDS, 16B/lane; LDS dest = wave-uniform base + lane*16
  __builtin_amdgcn_global_load_lds((const __attribute__((address_space(1))) void*)g,
                                   (__attribute__((address_space(3))) void*)l,
                                   16, 0, 0);
}

// ---------------- elementwise cast x -> bf16 ----------------
__global__ void cast_x_kernel(const float* __restrict__ x, short* __restrict__ xb, int n4) {
  int i = blockIdx.x * 256 + threadIdx.x;
  if (i >= n4) return;
  float4 v = ((const float4*)x)[i];
  short4v o; o.x = f2b(v.x); o.y = f2b(v.y); o.z = f2b(v.z); o.w = f2b(v.w);
  ((short4v*)xb)[i] = o;
}

// ---------------- all weight transposes in one launch ----------------
// grid (80, 32): x<32 wq | <40 wk | <48 wv | else wo. 64x64 LDS tile each.
__global__ void wtrans_all(const float* __restrict__ wq, const float* __restrict__ wk,
                           const float* __restrict__ wv, const float* __restrict__ wo,
                           short* __restrict__ WqkvT, short* __restrict__ woT) {
  __shared__ float tile[64][65];
  const int bx = blockIdx.x;
  const float* W; short* WT; int N, off, nb;
  if (bx < 32)      { W = wq; WT = WqkvT; N = 2048; off = 0;    nb = bx * 64; }
  else if (bx < 40) { W = wk; WT = WqkvT; N = 512;  off = 2048; nb = (bx - 32) * 64; }
  else if (bx < 48) { W = wv; WT = WqkvT; N = 512;  off = 2560; nb = (bx - 40) * 64; }
  else              { W = wo; WT = woT;   N = 2048; off = 0;    nb = (bx - 48) * 64; }
  const int kb = blockIdx.y * 64;
  const int tid = threadIdx.x;
  const int c = tid & 63, r0 = tid >> 6;
#pragma unroll
  for (int s = 0; s < 16; ++s) {
    int k = r0 + s * 4;
    tile[c][k] = W[(size_t)(kb + k) * N + nb + c];
  }
  __syncthreads();
#pragma unroll
  for (int s = 0; s < 16; ++s) {
    int n = r0 + s * 4;
    WT[(size_t)(off + nb + n) * 2048 + kb + c] = f2b(tile[n][c]);
  }
}

// ---------------- shared K-loop: 128(M)x64(N) tile, K=2048, BK=64, double-buffered ----------
// R0 structure (measured best: 42.5us for QKV): one __syncthreads per BK=64 stage,
// 32 barriers, per wave per stage 6 gl_lds + 12 ds_read_b128 + 16 MFMA.
// lA: 2 bufs x 2 k-panels x [128][32] = 16384 shorts; lB: 2 x 2 x [64][32] = 8192.
// T2 swizzle (verified R1/R2, conflicts 4.7M->0): LDS stays linear; the GLOBAL
// source column is pre-swizzled (slot ^= ((row%16)>>1)&3 -> swzc in callers),
// reads use q4x = q4 ^ ((l15>>1)&3).
__device__ __forceinline__ void gemm_loop_bk64(const short* __restrict__ Ag,
                                               const short* __restrict__ Bg,
                                               short* lA, short* lB,
                                               int w, int l15, int q4,
                                               f32x4 acc[2][4]) {
  const int K = 2048, NS = 32;  // stages of BK=64
  const int q4x = q4 ^ ((l15 >> 1) & 3);  // swizzled k-slot for LDS reads
  auto stage = [&](int s, int d) {
    const short* As = Ag + s * 64;
    const short* Bs = Bg + s * 64;
    short* a = lA + d * 8192 + w * 512;
    gl_lds16(As, a);                          // panel0 rows [w*16,+16)
    gl_lds16(As + 64 * K, a + 2048);          // panel0 rows +64
    gl_lds16(As + 32, a + 4096);              // panel1 rows [w*16,+16)
    gl_lds16(As + 64 * K + 32, a + 6144);     // panel1 rows +64
    short* bp = lB + d * 4096 + w * 512;
    gl_lds16(Bs, bp);                         // panel0
    gl_lds16(Bs + 32, bp + 2048);             // panel1
  };
  stage(0, 0);
  for (int s = 0; s < NS; ++s) {
    const int d = s & 1;
    __syncthreads();                          // drains stage(s) loads; frees buf d^1
    if (s + 1 < NS) stage(s + 1, d ^ 1);      // prefetch next stage (drained at NEXT barrier)
#pragma unroll
    for (int ks = 0; ks < 2; ++ks) {
      const short* ap = lA + d * 8192 + ks * 4096;
      const short* bp = lB + d * 4096 + ks * 2048;
      short8 af[2], bf[4];
#pragma unroll
      for (int mf = 0; mf < 2; ++mf) af[mf] = *(const short8*)(ap + (w * 32 + mf * 16 + l15) * 32 + q4x * 8);
#pragma unroll
      for (int nf = 0; nf < 4; ++nf) bf[nf] = *(const short8*)(bp + (nf * 16 + l15) * 32 + q4x * 8);
#pragma unroll
      for (int mf = 0; mf < 2; ++mf)
#pragma unroll
        for (int nf = 0; nf < 4; ++nf)
          acc[mf][nf] = __builtin_amdgcn_mfma_f32_16x16x32_bf16(af[mf], bf[nf], acc[mf][nf], 0, 0, 0);
    }
  }
}

// ---------------- fused QKV GEMM + bias + RoPE + scatter epilogue ----------------
// V-epilogue now writes the VT panel layout directly (vtrans2 kernel eliminated).
__launch_bounds__(256, 3)
__global__ void gemm_qkv(const short* __restrict__ A, const short* __restrict__ BT,
                         const float* __restrict__ bq, const float* __restrict__ bk,
                         const float* __restrict__ bv,
                         short* __restrict__ Qb, short* __restrict__ Kb,
                         short* __restrict__ VTb) {
  __shared__ __align__(16) short lA[16384];
  __shared__ __align__(16) short lB[8192];
  const int K = 2048;
  const int tid = threadIdx.x, lane = tid & 63, w = tid >> 6;
  const int q4 = lane >> 4, l15 = lane & 15;
  const int bn = blockIdx.x * 64, bm = blockIdx.y * 128;

  // staging source: swizzled k-slot (see gemm_loop_bk64 header comment)
  const int swzc = ((tid & 3) ^ ((tid >> 3) & 3)) << 3;
  const short* Ag = A + (size_t)(bm + (tid >> 2)) * K + swzc;
  const short* Bg = BT + (size_t)(bn + (tid >> 2)) * K + swzc;

  f32x4 acc[2][4];
  const f32x4 fz = {0.f, 0.f, 0.f, 0.f};
#pragma unroll
  for (int i = 0; i < 2; ++i)
#pragma unroll
    for (int j = 0; j < 4; ++j) acc[i][j] = fz;

  gemm_loop_bk64(Ag, Bg, lA, lB, w, l15, q4, acc);

  // ----- epilogue -----
  const float L2T = 0.4152410118609203f;          // log2(10000)/32
  const float theta_a = exp2_fast(-(float)l15 * L2T);
  const float theta_b = exp2_fast(-(float)(l15 + 16) * L2T);
  const float s2 = 0.18033688011112042f;          // 0.125 * log2(e): base-2 attn scores

  if (bn < 2048) {            // ---- Q: rope + scale -> Qb (b,h,t,64)
    const int h = bn >> 6;
    float bb0 = bq[bn + l15], bb1 = bq[bn + 16 + l15], bb2 = bq[bn + 32 + l15], bb3 = bq[bn + 48 + l15];
#pragma unroll
    for (int mf = 0; mf < 2; ++mf)
#pragma unroll
      for (int r = 0; r < 4; ++r) {
        int row = bm + w * 32 + mf * 16 + q4 * 4 + r;
        int batch = row >> 10, t = row & 1023;
        float pos = (float)(t + 1);
        float sa, ca, sb, cb;
        __sincosf(pos * theta_a, &sa, &ca);
        __sincosf(pos * theta_b, &sb, &cb);
        float x0 = acc[mf][0][r] + bb0, x2 = acc[mf][2][r] + bb2;
        float x1 = acc[mf][1][r] + bb1, x3 = acc[mf][3][r] + bb3;
        size_t base = ((size_t)(batch * 32 + h) * 1024 + t) * 64;
        Qb[base + l15]      = f2b((x0 * ca - x2 * sa) * s2);
        Qb[base + l15 + 32] = f2b((x2 * ca + x0 * sa) * s2);
        Qb[base + l15 + 16] = f2b((x1 * cb - x3 * sb) * s2);
        Qb[base + l15 + 48] = f2b((x3 * cb + x1 * sb) * s2);
      }
  } else if (bn < 2560) {     // ---- K: rope -> Kb (b,hkv)[dhalf][t][32]
    const int co = bn - 2048;
    const int hkv = co >> 6;
    float bb0 = bk[co + l15], bb1 = bk[co + 16 + l15], bb2 = bk[co + 32 + l15], bb3 = bk[co + 48 + l15];
#pragma unroll
    for (int mf = 0; mf < 2; ++mf)
#pragma unroll
      for (int r = 0; r < 4; ++r) {
        int row = bm + w * 32 + mf * 16 + q4 * 4 + r;
        int batch = row >> 10, t = row & 1023;
        float pos = (float)(t + 1);
        float sa, ca, sb, cb;
        __sincosf(pos * theta_a, &sa, &ca);
        __sincosf(pos * theta_b, &sb, &cb);
        float x0 = acc[mf][0][r] + bb0, x2 = acc[mf][2][r] + bb2;
        float x1 = acc[mf][1][r] + bb1, x3 = acc[mf][3][r] + bb3;
        size_t base = (size_t)(batch * 8 + hkv) * 65536 + t * 32;
        Kb[base + l15]              = f2b(x0 * ca - x2 * sa);  // d=l15      (half0)
        Kb[base + l15 + 16]         = f2b(x1 * cb - x3 * sb);  // d=l15+16   (half0)
        Kb[base + 32768 + l15]      = f2b(x2 * ca + x0 * sa);  // d=l15+32   (half1)
        Kb[base + 32768 + l15 + 16] = f2b(x3 * cb + x1 * sb);  // d=l15+48   (half1)
      }
  } else {                    // ---- V: bias -> VTb (b,hkv)[tchunk32][d64][32] directly
    const int co = bn - 2560;
    const int hkv = co >> 6;
    float bb[4];
#pragma unroll
    for (int nf = 0; nf < 4; ++nf) bb[nf] = bv[co + nf * 16 + l15];
    const int batch = (bm + w * 32) >> 10;          // bm%128==0, w*32<128: no crossing
    const size_t vbase = (size_t)(batch * 8 + hkv) * 65536;
#pragma unroll
    for (int mf = 0; mf < 2; ++mf) {
      const int t0 = (bm + w * 32 + mf * 16 + q4 * 4) & 1023;
      // t0&31 = mf*16+q4*4 <= 28, so r=0..3 stays inside the 32-chunk
      const size_t rbase = vbase + (size_t)(t0 >> 5) * 2048 + (t0 & 31);
#pragma unroll
      for (int nf = 0; nf < 4; ++nf) {
        short4v pk;
#pragma unroll
        for (int r = 0; r < 4; ++r) pk[r] = f2b(acc[mf][nf][r] + bb[nf]);
        *(short4v*)(VTb + rbase + (nf * 16 + l15) * 32) = pk;
      }
    }
  }
}

// ---------------- flash attention v5: block-cooperative LDS staging ----------------
// grid (8, 32, B); block = 128 q-rows; wave w owns rows [qt*128+w*32, +32).
// Per stage: 128 k-cols of K and V^T staged to LDS (8x global_load_lds), 2-barrier loop.
// Fixed-shift softmax P=2^(s2-16) (state is linear, no running max).
// T2 swizzle on K/V LDS tiles (pre-swizzled global source + q4x read slot).
#define PROW 72
__launch_bounds__(256, 3)
__global__ void attn5_kernel(const short* __restrict__ Qb, const short* __restrict__ Kb,
                             const short* __restrict__ VTb, short* __restrict__ AO) {
  __shared__ __align__(16) short lK[2][128 * 32];    // [dhalf][krow][32]
  __shared__ __align__(16) short lVT[4][64 * 32];    // [tchunk][d][32]
  __shared__ __align__(16) short lP[4][2][16 * PROW];
  const int tid = threadIdx.x, lane = tid & 63, w = tid >> 6;
  const int q4 = lane >> 4, l15 = lane & 15;
  const int q4x = q4 ^ ((l15 >> 1) & 3);             // swizzled k-slot for LDS reads
  const int swzc = ((tid & 3) ^ ((tid >> 3) & 3)) << 3;  // swizzled staging source col
  const int qt = (int)gridDim.x - 1 - (int)blockIdx.x;  // heavy blocks first
  const int h = blockIdx.y, b = blockIdx.z;
  const int hkv = h >> 2;
  const int qb = qt * 128 + w * 32;
  const int kdiag = qb >> 6;            // wave's diagonal 64-tile
  const int ns = qt + 1;                // stages of 128 k-cols

  const short* Qg = Qb + (size_t)(b * 32 + h) * 65536;
  const short* Kg = Kb + (size_t)(b * 8 + hkv) * 65536;
  const short* Vg = VTb + (size_t)(b * 8 + hkv) * 65536;

  short8 qf[2][2];
#pragma unroll
  for (int mf = 0; mf < 2; ++mf) {
    const short* qr = Qg + (size_t)(qb + mf * 16 + l15) * 64 + q4 * 8;
    qf[mf][0] = *(const short8*)(qr);
    qf[mf][1] = *(const short8*)(qr + 32);
  }

  const f32x4 fz = {0.f, 0.f, 0.f, 0.f};
  f32x4 o[2][4], ol[2];
#pragma unroll
  for (int mf = 0; mf < 2; ++mf) {
    ol[mf] = fz;
#pragma unroll
    for (int i = 0; i < 4; ++i) o[mf][i] = fz;
  }
  short8 ones;
#pragma unroll
  for (int i = 0; i < 8; ++i) ones[i] = (short)0x3F80;

  for (int s = 0; s < ns; ++s) {
    {
      const short* Ksrc = Kg + (size_t)(s * 128 + (tid >> 2)) * 32 + swzc;
      short* ldst = (short*)lK + w * 512;
      gl_lds16(Ksrc, ldst);
      gl_lds16(Ksrc + 64 * 32, ldst + 2048);
      gl_lds16(Ksrc + 32768, ldst + 4096);
      gl_lds16(Ksrc + 32768 + 64 * 32, ldst + 6144);
      const short* Vsrc = Vg + (size_t)(s * 4) * 2048 + (tid >> 2) * 32 + swzc;
      short* vdst = (short*)lVT + w * 512;
#pragma unroll
      for (int c = 0; c < 4; ++c) gl_lds16(Vsrc + c * 2048, vdst + c * 2048);
    }
    __syncthreads();

#pragma unroll
    for (int ki = 0; ki < 2; ++ki) {
      const int ktg = s * 2 + ki;
      if (ktg <= kdiag) {
        short8 kf0[4], kf1[4];
#pragma unroll
        for (int nt = 0; nt < 4; ++nt) {
          kf0[nt] = *(const short8*)((short*)lK + (ki * 64 + nt * 16 + l15) * 32 + q4x * 8);
          kf1[nt] = *(const short8*)((short*)lK + 4096 + (ki * 64 + nt * 16 + l15) * 32 + q4x * 8);
        }
        const bool diag = (ktg == kdiag);
#pragma unroll
        for (int mf = 0; mf < 2; ++mf) {
          f32x4 sv[4];
#pragma unroll
          for (int nt = 0; nt < 4; ++nt) {
            f32x4 z = __builtin_amdgcn_mfma_f32_16x16x32_bf16(qf[mf][0], kf0[nt], fz, 0, 0, 0);
            sv[nt] = __builtin_amdgcn_mfma_f32_16x16x32_bf16(qf[mf][1], kf1[nt], z, 0, 0, 0);
          }
          if (diag) {
#pragma unroll
            for (int r = 0; r < 4; ++r) {
              const int qrow = qb + mf * 16 + q4 * 4 + r;
              const int col = ktg * 64 + l15;
#pragma unroll
              for (int nt = 0; nt < 4; ++nt)
                if (col + nt * 16 > qrow) sv[nt][r] = -1e30f;
            }
          }
          short* lPm = lP[w][mf];
#pragma unroll
          for (int r = 0; r < 4; ++r)
#pragma unroll
            for (int nt = 0; nt < 4; ++nt)
              lPm[(q4 * 4 + r) * PROW + nt * 16 + l15] = f2b(exp2_fast(sv[nt][r] - 16.f));
        }

        short8 vf0[4], vf1[4];
#pragma unroll
        for (int dt = 0; dt < 4; ++dt) {
          vf0[dt] = *(const short8*)((short*)lVT + (2 * ki) * 2048 + (dt * 16 + l15) * 32 + q4x * 8);
          vf1[dt] = *(const short8*)((short*)lVT + (2 * ki + 1) * 2048 + (dt * 16 + l15) * 32 + q4x * 8);
        }
#pragma unroll
        for (int mf = 0; mf < 2; ++mf) {
          const short* lPm = lP[w][mf];
          short8 pf0 = *(const short8*)(lPm + l15 * PROW + q4 * 8);
          short8 pf1 = *(const short8*)(lPm + l15 * PROW + 32 + q4 * 8);
          ol[mf] = __builtin_amdgcn_mfma_f32_16x16x32_bf16(pf0, ones, ol[mf], 0, 0, 0);
          ol[mf] = __builtin_amdgcn_mfma_f32_16x16x32_bf16(pf1, ones, ol[mf], 0, 0, 0);
#pragma unroll
          for (int dt = 0; dt < 4; ++dt) {
            o[mf][dt] = __builtin_amdgcn_mfma_f32_16x16x32_bf16(pf0, vf0[dt], o[mf][dt], 0, 0, 0);
            o[mf][dt] = __builtin_amdgcn_mfma_f32_16x16x32_bf16(pf1, vf1[dt], o[mf][dt], 0, 0, 0);
          }
        }
      }
    }
    __syncthreads();
  }

#pragma unroll
  for (int mf = 0; mf < 2; ++mf)
#pragma unroll
    for (int r = 0; r < 4; ++r) {
      float inv = __builtin_amdgcn_rcpf(ol[mf][r]);
      int row = qb + mf * 16 + q4 * 4 + r;
#pragma unroll
      for (int dt = 0; dt < 4; ++dt)
        AO[(size_t)(b * 1024 + row) * 2048 + h * 64 + dt * 16 + l15] = f2b(o[mf][dt][r] * inv);
    }
}

// ---------------- output projection: BK=64 double-buffered, fp32 out + bias ----------------
__launch_bounds__(256, 3)
__global__ void gemm_out(const short* __restrict__ A, const short* __restrict__ BT,
                         float* __restrict__ C, const float* __restrict__ bias,
                         int N, int K) {
  __shared__ __align__(16) short lA[16384];
  __shared__ __align__(16) short lB[8192];
  const int tid = threadIdx.x, lane = tid & 63, w = tid >> 6;
  const int q4 = lane >> 4, l15 = lane & 15;
  const int bn = blockIdx.x * 64, bm = blockIdx.y * 128;

  const int swzc = ((tid & 3) ^ ((tid >> 3) & 3)) << 3;
  const short* Ag = A + (size_t)(bm + (tid >> 2)) * K + swzc;
  const short* Bg = BT + (size_t)(bn + (tid >> 2)) * K + swzc;

  f32x4 acc[2][4];
  const f32x4 fz = {0.f, 0.f, 0.f, 0.f};
#pragma unroll
  for (int i = 0; i < 2; ++i)
#pragma unroll
    for (int j = 0; j < 4; ++j) acc[i][j] = fz;

  gemm_loop_bk64(Ag, Bg, lA, lB, w, l15, q4, acc);

#pragma unroll
  for (int mf = 0; mf < 2; ++mf)
#pragma unroll
    for (int nf = 0; nf < 4; ++nf) {
      int col = bn + nf * 16 + l15;
      float bb = bias[col];
#pragma unroll
      for (int r = 0; r < 4; ++r) {
        int row = bm + w * 32 + mf * 16 + q4 * 4 + r;
        C[(size_t)row * N + col] = acc[mf][nf][r] + bb;
      }
    }
}

extern "C" void kernel_launch(void* const* d_in, const int* in_sizes, int n_in,
                              void* d_out, int out_size, void* d_ws, size_t ws_size,
                              hipStream_t stream) {
  const float* x  = (const float*)d_in[0];
  const float* wq = (const float*)d_in[1];
  const float* bq = (const float*)d_in[2];
  const float* wk = (const float*)d_in[3];
  const float* bk = (const float*)d_in[4];
  const float* wv = (const float*)d_in[5];
  const float* bv = (const float*)d_in[6];
  const float* wo = (const float*)d_in[7];
  const float* bo = (const float*)d_in[8];
  float* out = (float*)d_out;
  const int B = in_sizes[0] / (1024 * 2048);
  const int M = B * 1024;

  char* ws = (char*)d_ws;
  size_t off = 0;
  auto alloc = [&](size_t bytes) -> char* {
    char* p = ws + off;
    off += (bytes + 255) & ~(size_t)255;
    return p;
  };
  short* xb    = (short*)alloc((size_t)M * 2048 * 2);
  short* WqkvT = (short*)alloc((size_t)3072 * 2048 * 2);  // rows: wq^T | wk^T | wv^T (K-major)
  short* woT   = (short*)alloc((size_t)2048 * 2048 * 2);
  short* Qb    = (short*)alloc((size_t)B * 32 * 1024 * 64 * 2);    // (b,h,t,d)
  short* Kb    = (short*)alloc((size_t)B * 8 * 2 * 1024 * 32 * 2); // (b,hkv)[dhalf][t][32]
  short* VTb   = (short*)alloc((size_t)B * 8 * 32 * 64 * 32 * 2);  // (b,hkv)[tchunk][d][32]
  short* AO    = (short*)alloc((size_t)M * 2048 * 2);              // (b,t,E) bf16

  cast_x_kernel<<<(M * 2048 / 4 + 255) / 256, 256, 0, stream>>>(x, xb, M * 2048 / 4);
  wtrans_all<<<dim3(80, 32), 256, 0, stream>>>(wq, wk, wv, wo, WqkvT, woT);
  gemm_qkv<<<dim3(48, M / 128), 256, 0, stream>>>(xb, WqkvT, bq, bk, bv, Qb, Kb, VTb);
  attn5_kernel<<<dim3(8, 32, B), 256, 0, stream>>>(Qb, Kb, VTb, AO);
  gemm_out<<<dim3(32, M / 128), 256, 0, stream>>>(AO, woT, out, bo, 2048, 2048);
}